// Round 1
// 6708.664 us; speedup vs baseline: 2.2020x; 2.2020x over previous
//
#include <hip/hip_runtime.h>

// ---------------------------------------------------------------------------
// SimpleGRU on MI355X.
// bf16 MFMA everywhere. Persistent 256-WG kernel (1 WG/CU, LDS-bound).
// Partition: 4 batch-groups (32 rows) x 64 col-slices (16 cols/matrix).
// Cross-WG exchange per phase via MANUAL COHERENCE PROTOCOL:
//   data stores/loads = relaxed agent-scope atomics (sc0 sc1, through IF$),
//   completion via __syncthreads' implicit vmcnt(0) drain,
//   publication via one relaxed u16 flag (monotone round number) per WG,
//   consumption via per-wave parallel poll (lane l polls flag l, ballot).
// No __threadfence (avoids buffer_wbl2 L2 writeback per round), no atomicAdd.
// ---------------------------------------------------------------------------

typedef __attribute__((ext_vector_type(8))) short short8;
typedef __attribute__((ext_vector_type(4))) float f32x4;
typedef __attribute__((ext_vector_type(4))) unsigned short us4;
typedef unsigned short u16;
typedef unsigned long long u64;

// ws layout (bytes)
#define OFF_WH  0ul                 // 3 x [1024][1024] bf16 (transposed: Wt[c][k])
#define WH_SZ   2097152ul
#define OFF_WX  6291456ul           // 3 x [1024][512] bf16 (transposed)
#define WX_SZ   1048576ul
#define OFF_XB  9437184ul           // inputs bf16 [128*512][512]
#define OFF_HB  76546048ul          // h bf16 double buffer [2][128][1024]
#define OFF_RH  77070336ul          // Rh bf16 [128][1024]
#define OFF_FLG 77332480ul          // u16 flags[4][64] (monotone round counters)
#define WS_NEED 77332992ul

__device__ __forceinline__ u16 f2bf(float f) {
  unsigned u = __float_as_uint(f);
  u += 0x7FFFu + ((u >> 16) & 1u);      // round-to-nearest-even
  return (u16)(u >> 16);
}
__device__ __forceinline__ float sigm(float x) { return 1.f / (1.f + __expf(-x)); }
__device__ __forceinline__ float tanh_f(float x) {
  float e = __expf(2.f * x);
  return 1.f - 2.f / (e + 1.f);
}

// relaxed agent-scope 16B load (2 x dwordx2, sc0 sc1 -> served by IF$)
__device__ __forceinline__ short8 sysld8(const u16* p) {
  union { u64 q[2]; short8 s; } u;
  u.q[0] = __hip_atomic_load((const u64*)p,     __ATOMIC_RELAXED, __HIP_MEMORY_SCOPE_AGENT);
  u.q[1] = __hip_atomic_load((const u64*)p + 1, __ATOMIC_RELAXED, __HIP_MEMORY_SCOPE_AGENT);
  return u.s;
}

// ---- prep: transpose + cast the 6 weight matrices to bf16 Wt[c][k] ----
__global__ __launch_bounds__(256) void prep_wt(
    const float* __restrict__ Whr, const float* __restrict__ Whz,
    const float* __restrict__ Whh, const float* __restrict__ Wxr,
    const float* __restrict__ Wxz, const float* __restrict__ Wxh,
    unsigned char* __restrict__ ws) {
  __shared__ u16 tile[32][36];
  int id = blockIdx.x;
  const float* src; u16* dst; int K, tk, tc;
  if (id < 3072) {                       // W_h: 3 mats, 32x32 tiles of [1024][1024]
    int m = id >> 10, r = id & 1023;
    src = (m == 0) ? Whr : (m == 1) ? Whz : Whh;
    dst = (u16*)(ws + OFF_WH + (size_t)m * WH_SZ);
    K = 1024; tk = r >> 5; tc = r & 31;
  } else {                               // W_x: 3 mats, tiles of [512][1024]
    int r2 = id - 3072;
    int m = r2 >> 9, r = r2 & 511;
    src = (m == 0) ? Wxr : (m == 1) ? Wxz : Wxh;
    dst = (u16*)(ws + OFF_WX + (size_t)m * WX_SZ);
    K = 512; tk = r >> 5; tc = r & 31;
  }
  int t = threadIdx.x;
  int rr = t >> 3, c4 = (t & 7) * 4;
  const float* sp = src + (size_t)(tk * 32 + rr) * 1024 + tc * 32 + c4;
  tile[rr][c4 + 0] = f2bf(sp[0]);
  tile[rr][c4 + 1] = f2bf(sp[1]);
  tile[rr][c4 + 2] = f2bf(sp[2]);
  tile[rr][c4 + 3] = f2bf(sp[3]);
  __syncthreads();
  int rw = t >> 3, k4 = (t & 7) * 4;
  us4 o = { tile[k4 + 0][rw], tile[k4 + 1][rw], tile[k4 + 2][rw], tile[k4 + 3][rw] };
  *(us4*)(dst + (size_t)(tc * 32 + rw) * K + tk * 32 + k4) = o;
}

// ---- prep: cast inputs fp32 -> bf16 ----
__global__ __launch_bounds__(256) void prep_x(const float* __restrict__ xin,
                                              unsigned char* __restrict__ ws) {
  size_t id = (size_t)blockIdx.x * 256 + threadIdx.x;
  const float4* s = (const float4*)xin;
  float4 v = s[id];
  us4 o = { f2bf(v.x), f2bf(v.y), f2bf(v.z), f2bf(v.w) };
  *((us4*)(ws + OFF_XB) + id) = o;
}

// ---- prep: h_prev -> bf16 buf[1]; zero flags ----
__global__ __launch_bounds__(256) void prep_state(const float* __restrict__ hprev,
                                                  unsigned char* __restrict__ ws) {
  int id = blockIdx.x * 256 + threadIdx.x;   // 0..32767 (128 blocks)
  const float4* s = (const float4*)hprev;
  float4 v = s[id];
  us4 o = { f2bf(v.x), f2bf(v.y), f2bf(v.z), f2bf(v.w) };
  *((us4*)(ws + OFF_HB) + 32768 + id) = o;   // buf[1]
  if (blockIdx.x == 0 && threadIdx.x < 128)
    ((unsigned*)(ws + OFF_FLG))[threadIdx.x] = 0u;   // 512 B = all 256 u16 flags
}

// ---- main persistent GRU kernel ----
__global__ __launch_bounds__(256, 1) void gru_main(
    const float* __restrict__ hprev, const float* __restrict__ br_g,
    const float* __restrict__ bz_g, const float* __restrict__ bh_g,
    float* __restrict__ out, unsigned char* __restrict__ ws) {
  // LDS: W_h slices 3*[16 cols][1032 k] + W_x slices 3*[16][520] + reduce scratch
  __shared__ short wlds[74496];   // 148,992 B
  __shared__ float red[3072];     //  12,288 B  (total 161,280 < 160 KiB)

  const u16* __restrict__ xb = (const u16*)(ws + OFF_XB);
  u16* hb = (u16*)(ws + OFF_HB);
  u16* rhb = (u16*)(ws + OFF_RH);

  const int bid = blockIdx.x;
  const int gi = bid & 3;          // batch group: rows [32*gi, 32*gi+32)
  const int gj = bid >> 2;         // col group: cols [16*gj, 16*gj+16) per matrix
  const int tid = threadIdx.x;
  const int w = tid >> 6;          // wave 0..3
  const int l = tid & 63;
  const int ln = l & 15;           // MFMA n / C-col index
  const int lq = l >> 4;           // MFMA k-octet / C-row-quad
  const int mt = w & 1;            // M-tile (16 rows)
  const int kh = w >> 1;           // K-half; waves 0,1 = owners, 2,3 = helpers
  const bool owner = (w < 2);

  const u16* fbase = (const u16*)(ws + OFF_FLG) + gi * 64;
  u16* myflag = (u16*)(ws + OFF_FLG) + gi * 64 + gj;

  // ---- stage weight slices into LDS (once) ----
  for (int m = 0; m < 3; m++) {
    const u16* src = (const u16*)(ws + OFF_WH + (size_t)m * WH_SZ) + (size_t)gj * 16 * 1024;
    short* dst = wlds + m * 16512;
    #pragma unroll
    for (int it = 0; it < 8; it++) {
      int idx = it * 256 + tid;
      int c = idx >> 7, oc = idx & 127;
      *(short8*)(dst + c * 1032 + oc * 8) = *(const short8*)(src + c * 1024 + oc * 8);
    }
  }
  for (int m = 0; m < 3; m++) {
    const u16* src = (const u16*)(ws + OFF_WX + (size_t)m * WX_SZ) + (size_t)gj * 16 * 512;
    short* dst = wlds + 49536 + m * 8320;
    #pragma unroll
    for (int it = 0; it < 4; it++) {
      int idx = it * 256 + tid;
      int c = idx >> 6, oc = idx & 63;
      *(short8*)(dst + c * 520 + oc * 8) = *(const short8*)(src + c * 512 + oc * 8);
    }
  }
  __syncthreads();

  const int cg = gj * 16 + ln;                 // owned output column
  const int rb = gi * 32 + mt * 16 + lq * 4;   // owned C-rows base (owners)
  const int bA = gi * 32 + mt * 16 + ln;       // A-fragment row (m = lane&15)
  const float brv = br_g[cg], bzv = bz_g[cg], bhv = bh_g[cg];

  f32x4 hloc = {0.f, 0.f, 0.f, 0.f};
  if (owner) {
    #pragma unroll
    for (int r = 0; r < 4; r++) hloc[r] = hprev[(size_t)(rb + r) * 1024 + cg];
  }

  f32x4 xr_p = {0,0,0,0}, xz_p = {0,0,0,0}, xh_p = {0,0,0,0};
  f32x4 Zv = {0,0,0,0};

  // all waves poll: lane l watches flag l of this chain; monotone round numbers
  auto wait_flags = [&](unsigned tgt) {
    asm volatile("" ::: "memory");
    int g = 0;
    for (;;) {
      unsigned f = __hip_atomic_load(fbase + l, __ATOMIC_RELAXED, __HIP_MEMORY_SCOPE_AGENT);
      if (__ballot(f >= tgt) == ~0ull) break;
      if (++g > (1 << 17)) break;             // dead-man guard
    }
    __builtin_amdgcn_sched_barrier(0);
    asm volatile("" ::: "memory");
  };

  // x-projection for step t: xr/xz partials (red[1024:2048)), xh (red[2048:2560))
  auto xproj_rz = [&](int t) {
    f32x4 ar = {0,0,0,0}, az = {0,0,0,0};
    const u16* abase = xb + (size_t)bA * 262144 + (size_t)t * 512 + kh * 256 + lq * 8;
    const short* wr = wlds + 49536 + 0 * 8320 + ln * 520 + kh * 256 + lq * 8;
    const short* wz = wlds + 49536 + 1 * 8320 + ln * 520 + kh * 256 + lq * 8;
    #pragma unroll
    for (int kk = 0; kk < 8; kk++) {
      short8 a = *(const short8*)(abase + kk * 32);
      short8 b1 = *(const short8*)(wr + kk * 32);
      short8 b2 = *(const short8*)(wz + kk * 32);
      ar = __builtin_amdgcn_mfma_f32_16x16x32_bf16(a, b1, ar, 0, 0, 0);
      az = __builtin_amdgcn_mfma_f32_16x16x32_bf16(a, b2, az, 0, 0, 0);
    }
    if (!owner) {
      #pragma unroll
      for (int r = 0; r < 4; r++) {
        red[1024 + (mt * 2 + 0) * 256 + l * 4 + r] = ar[r];
        red[1024 + (mt * 2 + 1) * 256 + l * 4 + r] = az[r];
      }
    } else { xr_p = ar; xz_p = az; }
  };
  auto xproj_h = [&](int t) {
    f32x4 ah = {0,0,0,0};
    const u16* abase = xb + (size_t)bA * 262144 + (size_t)t * 512 + kh * 256 + lq * 8;
    const short* wh = wlds + 49536 + 2 * 8320 + ln * 520 + kh * 256 + lq * 8;
    #pragma unroll
    for (int kk = 0; kk < 8; kk++) {
      short8 a = *(const short8*)(abase + kk * 32);
      short8 b3 = *(const short8*)(wh + kk * 32);
      ah = __builtin_amdgcn_mfma_f32_16x16x32_bf16(a, b3, ah, 0, 0, 0);
    }
    if (!owner) {
      #pragma unroll
      for (int r = 0; r < 4; r++) red[2048 + mt * 256 + l * 4 + r] = ah[r];
    } else { xh_p = ah; }
  };

  // prologue: x-projection for t=0
  xproj_rz(0);
  xproj_h(0);
  __syncthreads();

  for (int t = 0; t < 512; t++) {
    const int pb = (t & 1) ^ 1;                 // h buffer holding h(t-1)
    const int tn = (t < 511) ? (t + 1) : 511;   // next-step x (clamped)

    // ---------------- Phase A: R, Z ----------------
    {
      const u16* abase = hb + (size_t)pb * 131072 + (size_t)bA * 1024 + kh * 512 + lq * 8;
      short8 afr[16];
      #pragma unroll
      for (int kk = 0; kk < 16; kk++) afr[kk] = sysld8(abase + kk * 32);  // batched IF$ loads
      f32x4 aR = {0,0,0,0}, aZ = {0,0,0,0};
      const short* w1 = wlds + 0 * 16512 + ln * 1032 + kh * 512 + lq * 8;
      const short* w2 = wlds + 1 * 16512 + ln * 1032 + kh * 512 + lq * 8;
      #pragma unroll
      for (int kk = 0; kk < 16; kk++) {
        short8 b1 = *(const short8*)(w1 + kk * 32);
        short8 b2 = *(const short8*)(w2 + kk * 32);
        aR = __builtin_amdgcn_mfma_f32_16x16x32_bf16(afr[kk], b1, aR, 0, 0, 0);
        aZ = __builtin_amdgcn_mfma_f32_16x16x32_bf16(afr[kk], b2, aZ, 0, 0, 0);
      }
      if (!owner) {
        #pragma unroll
        for (int r = 0; r < 4; r++) {
          red[(mt * 2 + 0) * 256 + l * 4 + r] = aR[r];
          red[(mt * 2 + 1) * 256 + l * 4 + r] = aZ[r];
        }
      }
      __syncthreads();
      if (owner) {
        #pragma unroll
        for (int r = 0; r < 4; r++) {
          float xr = xr_p[r] + red[1024 + (mt * 2 + 0) * 256 + l * 4 + r] + brv;
          float xz = xz_p[r] + red[1024 + (mt * 2 + 1) * 256 + l * 4 + r] + bzv;
          float R = sigm(aR[r] + red[(mt * 2 + 0) * 256 + l * 4 + r] + xr);
          float Z = sigm(aZ[r] + red[(mt * 2 + 1) * 256 + l * 4 + r] + xz);
          Zv[r] = Z;
          __hip_atomic_store(rhb + (size_t)(rb + r) * 1024 + cg, f2bf(R * hloc[r]),
                             __ATOMIC_RELAXED, __HIP_MEMORY_SCOPE_AGENT);
        }
      }
    }
    __syncthreads();   // implicit vmcnt(0): all sc1 Rh stores ack'd at IF$, WG-wide
    if (tid == 0)
      __hip_atomic_store(myflag, (u16)(2 * t + 1), __ATOMIC_RELAXED, __HIP_MEMORY_SCOPE_AGENT);
    asm volatile("" ::: "memory");
    xproj_rz(tn);                               // overlap exchange latency
    wait_flags(2u * (unsigned)t + 1u);

    // ---------------- Phase B: h~, h update ----------------
    {
      const u16* abase = rhb + (size_t)bA * 1024 + kh * 512 + lq * 8;
      short8 afr[16];
      #pragma unroll
      for (int kk = 0; kk < 16; kk++) afr[kk] = sysld8(abase + kk * 32);
      f32x4 aH = {0,0,0,0};
      const short* w3 = wlds + 2 * 16512 + ln * 1032 + kh * 512 + lq * 8;
      #pragma unroll
      for (int kk = 0; kk < 16; kk++) {
        short8 b3 = *(const short8*)(w3 + kk * 32);
        aH = __builtin_amdgcn_mfma_f32_16x16x32_bf16(afr[kk], b3, aH, 0, 0, 0);
      }
      if (!owner) {
        #pragma unroll
        for (int r = 0; r < 4; r++) red[mt * 256 + l * 4 + r] = aH[r];
      }
      __syncthreads();
      if (owner) {
        u16* hbw = hb + (size_t)(t & 1) * 131072;
        #pragma unroll
        for (int r = 0; r < 4; r++) {
          float xh = xh_p[r] + red[2048 + mt * 256 + l * 4 + r] + bhv;
          float ht = tanh_f(aH[r] + red[mt * 256 + l * 4 + r] + xh);
          float hn = Zv[r] * ht + (1.f - Zv[r]) * hloc[r];
          hloc[r] = hn;
          __hip_atomic_store(hbw + (size_t)(rb + r) * 1024 + cg, f2bf(hn),
                             __ATOMIC_RELAXED, __HIP_MEMORY_SCOPE_AGENT);
        }
      }
    }
    __syncthreads();   // implicit vmcnt(0): all sc1 h stores ack'd at IF$, WG-wide
    if (tid == 0)
      __hip_atomic_store(myflag, (u16)(2 * t + 2), __ATOMIC_RELAXED, __HIP_MEMORY_SCOPE_AGENT);
    asm volatile("" ::: "memory");
    if (owner) {       // fp32 out stores AFTER flag: drain off the critical path
      #pragma unroll
      for (int r = 0; r < 4; r++)
        out[((size_t)(rb + r) * 512 + (size_t)t) * 1024 + cg] = hloc[r];
    }
    xproj_h(tn);                                // overlap exchange latency
    wait_flags(2u * (unsigned)t + 2u);
  }
}

extern "C" void kernel_launch(void* const* d_in, const int* in_sizes, int n_in,
                              void* d_out, int out_size, void* d_ws, size_t ws_size,
                              hipStream_t stream) {
  const float* inputs = (const float*)d_in[0];
  const float* hprev  = (const float*)d_in[1];
  const float* Whr    = (const float*)d_in[2];
  const float* Wxr    = (const float*)d_in[3];
  const float* br     = (const float*)d_in[4];
  const float* Whz    = (const float*)d_in[5];
  const float* Wxz    = (const float*)d_in[6];
  const float* bz     = (const float*)d_in[7];
  const float* Whh    = (const float*)d_in[8];
  const float* Wxh    = (const float*)d_in[9];
  const float* bh     = (const float*)d_in[10];
  float* out = (float*)d_out;
  unsigned char* ws = (unsigned char*)d_ws;

  prep_wt<<<4608, 256, 0, stream>>>(Whr, Whz, Whh, Wxr, Wxz, Wxh, ws);
  prep_x<<<32768, 256, 0, stream>>>(inputs, ws);
  prep_state<<<128, 256, 0, stream>>>(hprev, ws);
  gru_main<<<256, 256, 0, stream>>>(hprev, br, bz, bh, out, ws);
}

// Round 4
// 5429.121 us; speedup vs baseline: 2.7210x; 1.2357x over previous
//
#include <hip/hip_runtime.h>

// ---------------------------------------------------------------------------
// SimpleGRU on MI355X.
// bf16 MFMA everywhere. Persistent 256-WG kernel (1 WG/CU, LDS-bound).
// Partition: 4 batch-groups (32 rows) x 64 col-slices (16 cols/matrix).
// Cross-WG exchange protocol (v4 = round-1-proven protocol + safe deltas):
//   producers: owners store Rh / h as relaxed agent-scope u16 stores
//     (write-through to IF$), drained by __syncthreads' implicit vmcnt(0),
//     then one u16 monotone round flag per WG.
//   consumers: wave 0 polls the group's 64 flags (lane-parallel, s_sleep
//     backoff, fail-soft dead-man), barrier-releases the WG; data loads are
//     16B inline-asm bypass loads (global_load_dwordx4 sc0 sc1) batched,
//     then s_waitcnt vmcnt(0) + sched_barrier(0)  [guide rule #18].
//   x-projections for step t+1 computed in the wait shadow.
// ---------------------------------------------------------------------------

typedef __attribute__((ext_vector_type(8))) short short8;
typedef __attribute__((ext_vector_type(4))) float f32x4;
typedef __attribute__((ext_vector_type(4))) unsigned short us4;
typedef unsigned short u16;
typedef unsigned long long u64;

// ws layout (bytes)
#define OFF_WH  0ul                 // 3 x [1024][1024] bf16 (transposed: Wt[c][k])
#define WH_SZ   2097152ul
#define OFF_WX  6291456ul           // 3 x [1024][512] bf16 (transposed)
#define WX_SZ   1048576ul
#define OFF_XB  9437184ul           // inputs bf16 [128*512][512]
#define OFF_HB  76546048ul          // h bf16 double buffer [2][128][1024]
#define OFF_RH  77070336ul          // Rh bf16 [128][1024]
#define OFF_FLG 77332480ul          // u16 flags[4][64] (monotone round counters)
#define WS_NEED 77332992ul

__device__ __forceinline__ u16 f2bf(float f) {
  unsigned u = __float_as_uint(f);
  u += 0x7FFFu + ((u >> 16) & 1u);      // round-to-nearest-even
  return (u16)(u >> 16);
}
__device__ __forceinline__ float sigm(float x) { return 1.f / (1.f + __expf(-x)); }
__device__ __forceinline__ float tanh_f(float x) {
  float e = __expf(2.f * x);
  return 1.f - 2.f / (e + 1.f);
}

// 16B L1/L2-bypass load (served by IF$, the device coherence point).
// No "memory" clobber: volatile asm still cannot cross __syncthreads
// (side-effecting), and data deps order the consumers; the explicit
// waitcnt+sched_barrier below fences the data arrival.
__device__ __forceinline__ short8 ld16_bypass(const u16* p) {
  short8 v;
  asm volatile("global_load_dwordx4 %0, %1, off sc0 sc1" : "=v"(v) : "v"(p));
  return v;
}

// ---- prep: transpose + cast the 6 weight matrices to bf16 Wt[c][k] ----
__global__ __launch_bounds__(256) void prep_wt(
    const float* __restrict__ Whr, const float* __restrict__ Whz,
    const float* __restrict__ Whh, const float* __restrict__ Wxr,
    const float* __restrict__ Wxz, const float* __restrict__ Wxh,
    unsigned char* __restrict__ ws) {
  __shared__ u16 tile[32][36];
  int id = blockIdx.x;
  const float* src; u16* dst; int K, tk, tc;
  if (id < 3072) {                       // W_h: 3 mats, 32x32 tiles of [1024][1024]
    int m = id >> 10, r = id & 1023;
    src = (m == 0) ? Whr : (m == 1) ? Whz : Whh;
    dst = (u16*)(ws + OFF_WH + (size_t)m * WH_SZ);
    K = 1024; tk = r >> 5; tc = r & 31;
  } else {                               // W_x: 3 mats, tiles of [512][1024]
    int r2 = id - 3072;
    int m = r2 >> 9, r = r2 & 511;
    src = (m == 0) ? Wxr : (m == 1) ? Wxz : Wxh;
    dst = (u16*)(ws + OFF_WX + (size_t)m * WX_SZ);
    K = 512; tk = r >> 5; tc = r & 31;
  }
  int t = threadIdx.x;
  int rr = t >> 3, c4 = (t & 7) * 4;
  const float* sp = src + (size_t)(tk * 32 + rr) * 1024 + tc * 32 + c4;
  tile[rr][c4 + 0] = f2bf(sp[0]);
  tile[rr][c4 + 1] = f2bf(sp[1]);
  tile[rr][c4 + 2] = f2bf(sp[2]);
  tile[rr][c4 + 3] = f2bf(sp[3]);
  __syncthreads();
  int rw = t >> 3, k4 = (t & 7) * 4;
  us4 o = { tile[k4 + 0][rw], tile[k4 + 1][rw], tile[k4 + 2][rw], tile[k4 + 3][rw] };
  *(us4*)(dst + (size_t)(tc * 32 + rw) * K + tk * 32 + k4) = o;
}

// ---- prep: cast inputs fp32 -> bf16 ----
__global__ __launch_bounds__(256) void prep_x(const float* __restrict__ xin,
                                              unsigned char* __restrict__ ws) {
  size_t id = (size_t)blockIdx.x * 256 + threadIdx.x;
  const float4* s = (const float4*)xin;
  float4 v = s[id];
  us4 o = { f2bf(v.x), f2bf(v.y), f2bf(v.z), f2bf(v.w) };
  *((us4*)(ws + OFF_XB) + id) = o;
}

// ---- prep: h_prev -> bf16 buf[1]; zero flags ----
__global__ __launch_bounds__(256) void prep_state(const float* __restrict__ hprev,
                                                  unsigned char* __restrict__ ws) {
  int id = blockIdx.x * 256 + threadIdx.x;   // 0..32767 (128 blocks)
  const float4* s = (const float4*)hprev;
  float4 v = s[id];
  us4 o = { f2bf(v.x), f2bf(v.y), f2bf(v.z), f2bf(v.w) };
  *((us4*)(ws + OFF_HB) + 32768 + id) = o;   // buf[1]
  if (blockIdx.x == 0 && threadIdx.x < 128)
    ((unsigned*)(ws + OFF_FLG))[threadIdx.x] = 0u;   // 512 B = all 256 u16 flags
}

// ---- main persistent GRU kernel ----
__global__ __launch_bounds__(256, 1) void gru_main(
    const float* __restrict__ hprev, const float* __restrict__ br_g,
    const float* __restrict__ bz_g, const float* __restrict__ bh_g,
    float* __restrict__ out, unsigned char* __restrict__ ws) {
  // LDS: W_h slices 3*[16 cols][1032 k] + W_x slices 3*[16][520] + reduce scratch
  __shared__ short wlds[74496];   // 148,992 B
  __shared__ float red[3072];     //  12,288 B  (total 161,280 < 160 KiB)

  const u16* __restrict__ xb = (const u16*)(ws + OFF_XB);
  u16* hb = (u16*)(ws + OFF_HB);
  u16* rhb = (u16*)(ws + OFF_RH);

  const int bid = blockIdx.x;
  const int gi = bid & 3;          // batch group: rows [32*gi, 32*gi+32)
  const int gj = bid >> 2;         // col group: cols [16*gj, 16*gj+16) per matrix
  const int tid = threadIdx.x;
  const int w = tid >> 6;          // wave 0..3
  const int l = tid & 63;
  const int ln = l & 15;           // MFMA n / C-col index
  const int lq = l >> 4;           // MFMA k-octet / C-row-quad
  const int mt = w & 1;            // M-tile (16 rows)
  const int kh = w >> 1;           // K-half; waves 0,1 = owners, 2,3 = helpers
  const bool owner = (w < 2);

  const u16* fbase = (const u16*)(ws + OFF_FLG) + gi * 64;
  u16* myflag = (u16*)(ws + OFF_FLG) + gi * 64 + gj;

  // ---- stage weight slices into LDS (once) ----
  for (int m = 0; m < 3; m++) {
    const u16* src = (const u16*)(ws + OFF_WH + (size_t)m * WH_SZ) + (size_t)gj * 16 * 1024;
    short* dst = wlds + m * 16512;
    #pragma unroll
    for (int it = 0; it < 8; it++) {
      int idx = it * 256 + tid;
      int c = idx >> 7, oc = idx & 127;
      *(short8*)(dst + c * 1032 + oc * 8) = *(const short8*)(src + c * 1024 + oc * 8);
    }
  }
  for (int m = 0; m < 3; m++) {
    const u16* src = (const u16*)(ws + OFF_WX + (size_t)m * WX_SZ) + (size_t)gj * 16 * 512;
    short* dst = wlds + 49536 + m * 8320;
    #pragma unroll
    for (int it = 0; it < 4; it++) {
      int idx = it * 256 + tid;
      int c = idx >> 6, oc = idx & 63;
      *(short8*)(dst + c * 520 + oc * 8) = *(const short8*)(src + c * 512 + oc * 8);
    }
  }
  __syncthreads();

  const int cg = gj * 16 + ln;                 // owned output column
  const int rb = gi * 32 + mt * 16 + lq * 4;   // owned C-rows base (owners)
  const int bA = gi * 32 + mt * 16 + ln;       // A-fragment row (m = lane&15)
  const float brv = br_g[cg], bzv = bz_g[cg], bhv = bh_g[cg];

  f32x4 hloc = {0.f, 0.f, 0.f, 0.f};
  if (owner) {
    #pragma unroll
    for (int r = 0; r < 4; r++) hloc[r] = hprev[(size_t)(rb + r) * 1024 + cg];
  }

  f32x4 xr_p = {0,0,0,0}, xz_p = {0,0,0,0}, xh_p = {0,0,0,0};
  f32x4 Zv = {0,0,0,0};

  // wave 0 polls the group's 64 flags (lane l watches flag l); s_sleep
  // backoff; FAIL-SOFT dead-man; barrier-release. Consumer data loads are
  // sc-bypass (IF$-served) so no cache invalidate is needed.
  auto wait_flags = [&](unsigned tgt) {
    if (w == 0) {
      int g = 0;
      for (;;) {
        unsigned f = __hip_atomic_load(fbase + l, __ATOMIC_RELAXED, __HIP_MEMORY_SCOPE_AGENT);
        if (__ballot(f >= tgt) == ~0ull) break;
        __builtin_amdgcn_s_sleep(2);
        if (++g > 8192) break;                // fail-soft dead-man guard
      }
    }
    __syncthreads();
    __builtin_amdgcn_sched_barrier(0);
    asm volatile("" ::: "memory");
  };

  // x-projection for step t: xr/xz partials (red[1024:2048)), xh (red[2048:2560))
  auto xproj_rz = [&](int t) {
    f32x4 ar = {0,0,0,0}, az = {0,0,0,0};
    const u16* abase = xb + (size_t)bA * 262144 + (size_t)t * 512 + kh * 256 + lq * 8;
    const short* wr = wlds + 49536 + 0 * 8320 + ln * 520 + kh * 256 + lq * 8;
    const short* wz = wlds + 49536 + 1 * 8320 + ln * 520 + kh * 256 + lq * 8;
    #pragma unroll
    for (int kk = 0; kk < 8; kk++) {
      short8 a = *(const short8*)(abase + kk * 32);
      short8 b1 = *(const short8*)(wr + kk * 32);
      short8 b2 = *(const short8*)(wz + kk * 32);
      ar = __builtin_amdgcn_mfma_f32_16x16x32_bf16(a, b1, ar, 0, 0, 0);
      az = __builtin_amdgcn_mfma_f32_16x16x32_bf16(a, b2, az, 0, 0, 0);
    }
    if (!owner) {
      #pragma unroll
      for (int r = 0; r < 4; r++) {
        red[1024 + (mt * 2 + 0) * 256 + l * 4 + r] = ar[r];
        red[1024 + (mt * 2 + 1) * 256 + l * 4 + r] = az[r];
      }
    } else { xr_p = ar; xz_p = az; }
  };
  auto xproj_h = [&](int t) {
    f32x4 ah = {0,0,0,0};
    const u16* abase = xb + (size_t)bA * 262144 + (size_t)t * 512 + kh * 256 + lq * 8;
    const short* wh = wlds + 49536 + 2 * 8320 + ln * 520 + kh * 256 + lq * 8;
    #pragma unroll
    for (int kk = 0; kk < 8; kk++) {
      short8 a = *(const short8*)(abase + kk * 32);
      short8 b3 = *(const short8*)(wh + kk * 32);
      ah = __builtin_amdgcn_mfma_f32_16x16x32_bf16(a, b3, ah, 0, 0, 0);
    }
    if (!owner) {
      #pragma unroll
      for (int r = 0; r < 4; r++) red[2048 + mt * 256 + l * 4 + r] = ah[r];
    } else { xh_p = ah; }
  };

  // prologue: x-projection for t=0
  xproj_rz(0);
  xproj_h(0);
  __syncthreads();

  for (int t = 0; t < 512; t++) {
    const int pb = (t & 1) ^ 1;                 // h buffer holding h(t-1)
    const int tn = (t < 511) ? (t + 1) : 511;   // next-step x (clamped)

    // ---------------- Phase A: R, Z ----------------
    {
      const u16* abase = hb + (size_t)pb * 131072 + (size_t)bA * 1024 + kh * 512 + lq * 8;
      short8 afr[16];
      #pragma unroll
      for (int kk = 0; kk < 16; kk++) afr[kk] = ld16_bypass(abase + kk * 32);
      asm volatile("s_waitcnt vmcnt(0)" ::: "memory");   // all 16 loads landed
      __builtin_amdgcn_sched_barrier(0);                 // rule #18 fence
      f32x4 aR = {0,0,0,0}, aZ = {0,0,0,0};
      const short* w1 = wlds + 0 * 16512 + ln * 1032 + kh * 512 + lq * 8;
      const short* w2 = wlds + 1 * 16512 + ln * 1032 + kh * 512 + lq * 8;
      #pragma unroll
      for (int kk = 0; kk < 16; kk++) {
        short8 b1 = *(const short8*)(w1 + kk * 32);
        short8 b2 = *(const short8*)(w2 + kk * 32);
        aR = __builtin_amdgcn_mfma_f32_16x16x32_bf16(afr[kk], b1, aR, 0, 0, 0);
        aZ = __builtin_amdgcn_mfma_f32_16x16x32_bf16(afr[kk], b2, aZ, 0, 0, 0);
      }
      if (!owner) {
        #pragma unroll
        for (int r = 0; r < 4; r++) {
          red[(mt * 2 + 0) * 256 + l * 4 + r] = aR[r];
          red[(mt * 2 + 1) * 256 + l * 4 + r] = aZ[r];
        }
      }
      __syncthreads();
      if (owner) {
        #pragma unroll
        for (int r = 0; r < 4; r++) {
          float xr = xr_p[r] + red[1024 + (mt * 2 + 0) * 256 + l * 4 + r] + brv;
          float xz = xz_p[r] + red[1024 + (mt * 2 + 1) * 256 + l * 4 + r] + bzv;
          float R = sigm(aR[r] + red[(mt * 2 + 0) * 256 + l * 4 + r] + xr);
          float Z = sigm(aZ[r] + red[(mt * 2 + 1) * 256 + l * 4 + r] + xz);
          Zv[r] = Z;
          __hip_atomic_store(rhb + (size_t)(rb + r) * 1024 + cg, f2bf(R * hloc[r]),
                             __ATOMIC_RELAXED, __HIP_MEMORY_SCOPE_AGENT);
        }
      }
    }
    __syncthreads();   // implicit vmcnt(0): all Rh stores ack'd at IF$, WG-wide
    if (tid == 0)
      __hip_atomic_store(myflag, (u16)(2 * t + 1), __ATOMIC_RELAXED, __HIP_MEMORY_SCOPE_AGENT);
    asm volatile("" ::: "memory");
    xproj_rz(tn);                               // overlap exchange latency
    wait_flags(2u * (unsigned)t + 1u);

    // ---------------- Phase B: h~, h update ----------------
    {
      const u16* abase = rhb + (size_t)bA * 1024 + kh * 512 + lq * 8;
      short8 afr[16];
      #pragma unroll
      for (int kk = 0; kk < 16; kk++) afr[kk] = ld16_bypass(abase + kk * 32);
      asm volatile("s_waitcnt vmcnt(0)" ::: "memory");
      __builtin_amdgcn_sched_barrier(0);
      f32x4 aH = {0,0,0,0};
      const short* w3 = wlds + 2 * 16512 + ln * 1032 + kh * 512 + lq * 8;
      #pragma unroll
      for (int kk = 0; kk < 16; kk++) {
        short8 b3 = *(const short8*)(w3 + kk * 32);
        aH = __builtin_amdgcn_mfma_f32_16x16x32_bf16(afr[kk], b3, aH, 0, 0, 0);
      }
      if (!owner) {
        #pragma unroll
        for (int r = 0; r < 4; r++) red[mt * 256 + l * 4 + r] = aH[r];
      }
      __syncthreads();
      if (owner) {
        u16* hbw = hb + (size_t)(t & 1) * 131072;
        #pragma unroll
        for (int r = 0; r < 4; r++) {
          float xh = xh_p[r] + red[2048 + mt * 256 + l * 4 + r] + bhv;
          float ht = tanh_f(aH[r] + red[mt * 256 + l * 4 + r] + xh);
          float hn = Zv[r] * ht + (1.f - Zv[r]) * hloc[r];
          hloc[r] = hn;
          __hip_atomic_store(hbw + (size_t)(rb + r) * 1024 + cg, f2bf(hn),
                             __ATOMIC_RELAXED, __HIP_MEMORY_SCOPE_AGENT);
        }
      }
    }
    __syncthreads();   // implicit vmcnt(0): all h stores ack'd at IF$, WG-wide
    if (tid == 0)
      __hip_atomic_store(myflag, (u16)(2 * t + 2), __ATOMIC_RELAXED, __HIP_MEMORY_SCOPE_AGENT);
    asm volatile("" ::: "memory");
    if (owner) {       // fp32 out stores AFTER flag: drain off the critical path
      #pragma unroll
      for (int r = 0; r < 4; r++)
        out[((size_t)(rb + r) * 512 + (size_t)t) * 1024 + cg] = hloc[r];
    }
    xproj_h(tn);                                // overlap exchange latency
    wait_flags(2u * (unsigned)t + 2u);
  }
}

extern "C" void kernel_launch(void* const* d_in, const int* in_sizes, int n_in,
                              void* d_out, int out_size, void* d_ws, size_t ws_size,
                              hipStream_t stream) {
  const float* inputs = (const float*)d_in[0];
  const float* hprev  = (const float*)d_in[1];
  const float* Whr    = (const float*)d_in[2];
  const float* Wxr    = (const float*)d_in[3];
  const float* br     = (const float*)d_in[4];
  const float* Whz    = (const float*)d_in[5];
  const float* Wxz    = (const float*)d_in[6];
  const float* bz     = (const float*)d_in[7];
  const float* Whh    = (const float*)d_in[8];
  const float* Wxh    = (const float*)d_in[9];
  const float* bh     = (const float*)d_in[10];
  float* out = (float*)d_out;
  unsigned char* ws = (unsigned char*)d_ws;

  prep_wt<<<4608, 256, 0, stream>>>(Whr, Whz, Whh, Wxr, Wxz, Wxh, ws);
  prep_x<<<32768, 256, 0, stream>>>(inputs, ws);
  prep_state<<<128, 256, 0, stream>>>(hprev, ws);
  gru_main<<<256, 256, 0, stream>>>(hprev, br, bz, bh, out, ws);
}